// Round 2
// baseline (929.012 us; speedup 1.0000x reference)
//
#include <hip/hip_runtime.h>

#define NN 1024
#define TT 256
#define MAXDEG 96

typedef unsigned short u16;
typedef unsigned int u32;

// ---------------- prep: build bank-scheduled interleaved neighbor table ----------------
// For node n (lane l = n&63), slot k should read LDS bank (l+k)&31 so that the 64
// lanes of a wave cover each bank exactly twice (2-way is conflict-free on gfx950).
// Greedy: place each neighbor m at the first free slot k with (k+l)%32 == (m%32),
// overflow anywhere free. Stored value = byte offset (m*4). Sentinel slots point at
// zeroed LDS cells NN..NN+31 chosen to land exactly on the target bank.
__global__ __launch_bounds__(64) void build_kernel(const float* __restrict__ adj,
                                                   u16* __restrict__ nbr8,
                                                   float* __restrict__ indeg,
                                                   int* __restrict__ pdeg_out)
{
    __shared__ u16 neigh[64][MAXDEG];
    __shared__ u16 slots[64][MAXDEG];
    const int n  = blockIdx.x * 64 + threadIdx.x;   // node / column
    const int tl = threadIdx.x;
    const int l  = n & 63;                          // lane this node maps to in sim

    int deg = 0, cap = 0;
    for (int m = 0; m < NN; ++m) {
        if (adj[m * NN + n] != 0.0f) {
            if (cap < MAXDEG) neigh[tl][cap++] = (u16)m;
            ++deg;
        }
    }
    const int pd = (cap + 7) & ~7;                  // tight padded degree (may be 0)

    for (int k = 0; k < pd; ++k) slots[tl][k] = 0xFFFF;

    // pass 1: bank-matched placement
    int no = 0;                                     // overflow count (reuse neigh[0..no))
    for (int j = 0; j < cap; ++j) {
        u16 m = neigh[tl][j];
        int r = ((int)(m & 31) - l) & 31;
        int placed = 0;
        for (int k = r; k < pd; k += 32) {
            if (slots[tl][k] == 0xFFFF) { slots[tl][k] = m; placed = 1; break; }
        }
        if (!placed) neigh[tl][no++] = m;
    }
    // pass 2: overflow into any free slot
    int fk = 0;
    for (int j = 0; j < no; ++j) {
        while (slots[tl][fk] != 0xFFFF) ++fk;
        slots[tl][fk] = neigh[tl][j];
    }
    // write out as byte offsets, sentinel -> bank-matched zero cell
    for (int k = 0; k < pd; ++k) {
        u16 v = slots[tl][k];
        u16 store = (v == 0xFFFF) ? (u16)((NN + ((l + k) & 31)) * 4) : (u16)(v * 4);
        nbr8[((k >> 3) << 13) + (n << 3) + (k & 7)] = store;
    }
    indeg[n]    = (float)deg;
    pdeg_out[n] = pd;
}

// ---------------- main simulation: one block per sequence, one thread per node ----------------
__global__ __launch_bounds__(1024) void sim_kernel(
    const float* __restrict__ x0, const float* __restrict__ t,
    const float* __restrict__ speed, const float* __restrict__ vola,
    const float* __restrict__ noise, const int* __restrict__ items,
    const u16* __restrict__ nbr8, const float* __restrict__ indeg,
    const int* __restrict__ pdeg, float* __restrict__ out)
{
    __shared__ float xA[NN + 32];       // double buffer A (+32 zeroed sentinel cells)
    __shared__ float xB[NN + 32];
    __shared__ float4 cst[TT - 1];      // per-step {e, scale, item_as_float, -}

    const int s = blockIdx.x;
    const int n = threadIdx.x;

    const float sp = speed[s];
    const float vo = vola[s];

    if (n < TT - 1) {
        float t0 = t[s * TT + n], t1 = t[s * TT + n + 1];
        float dt = t1 - t0;
        float e  = expf(-sp * dt);
        float sc = vo * sqrtf((1.0f - e * e) / (2.0f * sp + 1e-6f));
        int   it = items[s * TT + n + 1];
        cst[n] = make_float4(e, sc, __int_as_float(it), 0.0f);
    }

    const float x0n = x0[n];
    xA[n] = x0n;
    if (n < 32) { xA[NN + n] = 0.0f; xB[NN + n] = 0.0f; }
    out[(size_t)(s * TT) * NN + n] = x0n;

    const int item0 = items[s * TT];
    float a_f = (n == item0) ? 1.0f : 0.0f;   // feat[...,0] attempts (owner-only state)
    float s_f = 0.0f;                          // feat[...,1] successes
    float x_own = x0n;

    const float dg = indeg[n];
    const int ngrp = pdeg[n] >> 3;
    const float invdeg2 = 0.35f / (dg + 1e-7f);   // OMEGA*GAMMA / (in_deg+1e-7)

    const uint4* __restrict__ nb = (const uint4*)(nbr8 + (n << 3));
    const float* __restrict__ nzp = noise + (size_t)s * (TT - 1) * NN + n;

    __syncthreads();

#define STEP(SRC, DST, I)                                                      \
    {                                                                          \
        const int i_ = (I);                                                    \
        float4 c = cst[i_];                                                    \
        float nz = nzp[(size_t)i_ * NN] * c.y;                                 \
        float acc = 0.0f;                                                      \
        const char* xc = (const char*)(SRC);                                   \
        for (int g = 0; g < ngrp; ++g) {                                       \
            uint4 w = nb[(size_t)g << 10];                                     \
            acc += *(const float*)(xc + (w.x & 0xFFFFu));                      \
            acc += *(const float*)(xc + (w.x >> 16));                          \
            acc += *(const float*)(xc + (w.y & 0xFFFFu));                      \
            acc += *(const float*)(xc + (w.y >> 16));                          \
            acc += *(const float*)(xc + (w.z & 0xFFFFu));                      \
            acc += *(const float*)(xc + (w.z >> 16));                          \
            acc += *(const float*)(xc + (w.w & 0xFFFFu));                      \
            acc += *(const float*)(xc + (w.w >> 16));                          \
        }                                                                      \
        float r = s_f / (a_f + 1e-6f);                                         \
        float level = fmaf(acc, invdeg2, 0.5f * r * r);                        \
        float xn = fmaf(x_own, c.x, fmaf(1.0f - c.x, level, nz));              \
        out[((size_t)s * TT + i_ + 1) * NN + n] = xn;                          \
        (DST)[n] = xn;                                                         \
        if (n == __float_as_int(c.z)) {                                        \
            a_f += 1.0f;                                                       \
            s_f += (xn >= 0.0f) ? 1.0f : 0.0f;                                 \
        }                                                                      \
        x_own = xn;                                                            \
        __syncthreads();                                                       \
    }

    for (int i = 0; i < TT - 2; i += 2) {
        STEP(xA, xB, i);
        STEP(xB, xA, i + 1);
    }
    STEP(xA, xB, TT - 2);   // step 254 (even), A -> B
#undef STEP
}

extern "C" void kernel_launch(void* const* d_in, const int* in_sizes, int n_in,
                              void* d_out, int out_size, void* d_ws, size_t ws_size,
                              hipStream_t stream)
{
    const float* x0    = (const float*)d_in[0];
    const float* t     = (const float*)d_in[1];
    const float* speed = (const float*)d_in[2];
    const float* vola  = (const float*)d_in[3];
    const float* adj   = (const float*)d_in[4];
    const float* noise = (const float*)d_in[5];
    const int*   items = (const int*)d_in[6];
    float* out = (float*)d_out;

    char* ws = (char*)d_ws;
    float* indeg = (float*)ws;                 // 4 KB
    int*   pdeg  = (int*)(ws + 4096);          // 4 KB
    u16*   nbr8  = (u16*)(ws + 8192);          // 192 KB (12 groups * 8192 u16)

    build_kernel<<<16, 64, 0, stream>>>(adj, nbr8, indeg, pdeg);
    sim_kernel<<<64, 1024, 0, stream>>>(x0, t, speed, vola, noise, items,
                                        nbr8, indeg, pdeg, out);
}

// Round 4
// 576.399 us; speedup vs baseline: 1.6118x; 1.6118x over previous
//
#include <hip/hip_runtime.h>

#define NN 1024
#define TT 256
#define MAXDEG 96

typedef unsigned short u16;

// ---------------- ws layout helpers ----------------
// cnt_part : 16*1024 int  (64 KB)
// deg      : 1024 int
// pdeg     : 1024 int   (padded degree, >=16, mult of 8)
// rank_of  : 1024 int
// node_of  : 1024 int
// ngrp_r   : 1024 int   (indexed by rank)
// invd_r   : 1024 float (indexed by rank)
// nbrC     : 1024*96 u16 (compact per-node neighbor list, 192 KB)
// nbr8     : 12*1024*8 u16 (scheduled table indexed by rank, 192 KB)

// ---- K1: per-chunk nonzero counts of each adj column (coalesced) ----
__global__ __launch_bounds__(64) void k1_count(const float* __restrict__ adj,
                                               int* __restrict__ cnt_part)
{
    int tid = blockIdx.x * 64 + threadIdx.x;   // 0..16383
    int chunk = tid >> 10;
    int n = tid & 1023;
    int c = 0;
    for (int j = 0; j < 64; ++j)
        c += (adj[(chunk * 64 + j) * NN + n] != 0.0f) ? 1 : 0;
    cnt_part[chunk * NN + n] = c;
}

// ---- K2: totals -> deg, pdeg ----
__global__ __launch_bounds__(256) void k2_totals(const int* __restrict__ cnt_part,
                                                 int* __restrict__ deg,
                                                 int* __restrict__ pdeg)
{
    int n = blockIdx.x * 256 + threadIdx.x;
    int tot = 0;
    for (int c = 0; c < 16; ++c) tot += cnt_part[c * NN + n];
    deg[n] = tot;
    int cap = tot < MAXDEG ? tot : MAXDEG;
    int pd = (cap + 7) & ~7;
    if (pd < 16) pd = 16;                 // min 2 groups (lets sim unroll 2 unconditionally)
    pdeg[n] = pd;
}

// ---- K3: stable descending-degree rank ----
__global__ __launch_bounds__(256) void k3_rank(const int* __restrict__ pdeg,
                                               int* __restrict__ rank_of,
                                               int* __restrict__ node_of)
{
    int n = blockIdx.x * 256 + threadIdx.x;
    int my = pdeg[n];
    int r = 0;
    for (int m = 0; m < NN; ++m) {
        int pm = pdeg[m];
        r += (pm > my) || (pm == my && m < n);
    }
    rank_of[n] = r;
    node_of[r] = n;
}

// ---- K4: fill compact neighbor lists (coalesced column scan) ----
__global__ __launch_bounds__(64) void k4_fill(const float* __restrict__ adj,
                                              const int* __restrict__ cnt_part,
                                              u16* __restrict__ nbrC)
{
    int tid = blockIdx.x * 64 + threadIdx.x;
    int chunk = tid >> 10;
    int n = tid & 1023;
    int pos = 0;
    for (int c = 0; c < chunk; ++c) pos += cnt_part[c * NN + n];
    for (int j = 0; j < 64; ++j) {
        int m = chunk * 64 + j;
        if (adj[m * NN + n] != 0.0f) {
            if (pos < MAXDEG) nbrC[n * MAXDEG + pos] = (u16)m;
            ++pos;
        }
    }
}

// ---- K5: greedy bank schedule, write table indexed by rank ----
// lane of node n in sim = rank_of[n] & 63; slot k targets bank (lane+k)&31 so each
// instruction's 64 lanes cover each bank exactly 2x (free on gfx950).
__global__ __launch_bounds__(64) void k5_sched(const u16* __restrict__ nbrC,
                                               const int* __restrict__ deg,
                                               const int* __restrict__ pdeg,
                                               const int* __restrict__ rank_of,
                                               u16* __restrict__ nbr8,
                                               int* __restrict__ ngrp_r,
                                               float* __restrict__ invd_r)
{
    __shared__ u16 neigh[64][MAXDEG];
    __shared__ u16 slots[64][MAXDEG];
    const int tl = threadIdx.x;
    const int n  = blockIdx.x * 64 + tl;
    const int r  = rank_of[n];
    const int l  = r & 63;
    const int dg = deg[n];
    const int cap = dg < MAXDEG ? dg : MAXDEG;
    const int pd = pdeg[n];

    for (int j = 0; j < cap; ++j) neigh[tl][j] = nbrC[n * MAXDEG + j];
    for (int k = 0; k < pd; ++k) slots[tl][k] = 0xFFFF;

    int no = 0;
    for (int j = 0; j < cap; ++j) {
        u16 m = neigh[tl][j];
        int rr = ((int)(m & 31) - l) & 31;
        int placed = 0;
        for (int k = rr; k < pd; k += 32)
            if (slots[tl][k] == 0xFFFF) { slots[tl][k] = m; placed = 1; break; }
        if (!placed) neigh[tl][no++] = m;
    }
    int fk = 0;
    for (int j = 0; j < no; ++j) {
        while (slots[tl][fk] != 0xFFFF) ++fk;
        slots[tl][fk] = neigh[tl][j];
    }
    for (int k = 0; k < pd; ++k) {
        u16 v = slots[tl][k];
        u16 store = (v == 0xFFFF) ? (u16)((NN + ((l + k) & 31)) * 4) : (u16)(v * 4);
        nbr8[((k >> 3) << 13) + (r << 3) + (k & 7)] = store;
    }
    ngrp_r[r] = pd >> 3;
    invd_r[r] = 0.35f / ((float)dg + 1e-7f);   // OMEGA*GAMMA/(in_deg+1e-7)
}

// ---------------- main simulation ----------------
__global__ __launch_bounds__(1024) void sim_kernel(
    const float* __restrict__ x0, const float* __restrict__ t,
    const float* __restrict__ speed, const float* __restrict__ vola,
    const float* __restrict__ noise, const int* __restrict__ items,
    const u16* __restrict__ nbr8, const int* __restrict__ node_of,
    const int* __restrict__ ngrp_r, const float* __restrict__ invd_r,
    float* __restrict__ out)
{
    __shared__ float xb[2][NN + 32];    // x buffers indexed by NODE id, +32 zero sentinels
    __shared__ float nzb[2][NN];        // staged noise, indexed by node id
    __shared__ float4 cst[TT - 1];      // per-step {e, scale, item_as_float, -}

    const int s   = blockIdx.x;
    const int tid = threadIdx.x;

    const float sp = speed[s];
    const float vo = vola[s];

    if (tid < TT - 1) {
        float t0 = t[s * TT + tid], t1 = t[s * TT + tid + 1];
        float dt = t1 - t0;
        float e  = expf(-sp * dt);
        float sc = vo * sqrtf((1.0f - e * e) / (2.0f * sp + 1e-6f));
        int   it = items[s * TT + tid + 1];
        cst[tid] = make_float4(e, sc, __int_as_float(it), 0.0f);
    }

    const float x0n = x0[tid];
    xb[0][tid] = x0n;
    if (tid < 32) { xb[0][NN + tid] = 0.0f; xb[1][NN + tid] = 0.0f; }

    const float* __restrict__ nzp = noise + (size_t)s * (TT - 1) * NN + tid;
    nzb[0][tid] = nzp[0];

    float* __restrict__ outp = out + (size_t)s * TT * NN + tid;
    outp[0] = x0n;

    const int   m    = node_of[tid];      // node this thread simulates
    const int   ng   = ngrp_r[tid];
    const float invd = invd_r[tid];
    const int   item0 = items[s * TT];
    float a_f = (m == item0) ? 1.0f : 0.0f;
    float s_f = 0.0f;

    // preload neighbor index groups 0..5 into registers (uint4 = 8 u16 byte-offsets)
    const uint4* __restrict__ nb = (const uint4*)nbr8 + tid;   // group stride 1024
    uint4 q0 = nb[0];
    uint4 q1 = nb[1024];
    uint4 q2 = nb[2048];
    uint4 q3 = nb[3072];
    uint4 q4 = nb[4096];
    uint4 q5 = nb[5120];

    __syncthreads();

    float x_own = xb[0][m];               // scatter read once

#define G8(V)                                                   \
    acc += *(const float*)(xc + ((V).x & 0xFFFFu));             \
    acc += *(const float*)(xc + ((V).x >> 16));                 \
    acc += *(const float*)(xc + ((V).y & 0xFFFFu));             \
    acc += *(const float*)(xc + ((V).y >> 16));                 \
    acc += *(const float*)(xc + ((V).z & 0xFFFFu));             \
    acc += *(const float*)(xc + ((V).z >> 16));                 \
    acc += *(const float*)(xc + ((V).w & 0xFFFFu));             \
    acc += *(const float*)(xc + ((V).w >> 16));

    for (int i = 0; i < TT - 1; ++i) {
        const float* __restrict__ src = xb[i & 1];
        float* __restrict__ dst       = xb[(i + 1) & 1];
        const float4 c = cst[i];

        float xi_lin = src[tid];          // previous step's value of node `tid` (linear read)

        float acc = 0.0f;
        const char* xc = (const char*)src;
        G8(q0); G8(q1);
        if (ng > 2) {
            G8(q2);
            if (ng > 3) {
                G8(q3);
                if (ng > 4) {
                    G8(q4);
                    if (ng > 5) {
                        G8(q5);
                        for (int g = 6; g < ng; ++g) { uint4 qv = nb[g << 10]; G8(qv); }
                    }
                }
            }
        }

        float nz = nzb[i & 1][m] * c.y;
        float r  = s_f / (a_f + 1e-6f);
        float level = fmaf(acc, invd, 0.5f * r * r);
        float xn = fmaf(x_own, c.x, fmaf(1.0f - c.x, level, nz));

        dst[m] = xn;                      // scatter write
        if (i) outp[(size_t)i * NN] = xi_lin;   // coalesced, 1-step delayed
        if (i < TT - 2) nzb[(i + 1) & 1][tid] = nzp[(size_t)(i + 1) * NN];

        if (m == __float_as_int(c.z)) {
            a_f += 1.0f;
            s_f += (xn >= 0.0f) ? 1.0f : 0.0f;
        }
        x_own = xn;
        __syncthreads();
    }
#undef G8

    outp[(size_t)(TT - 1) * NN] = xb[1][tid];   // x_255 lives in buffer 1 (255 = odd parity dst)
}

extern "C" void kernel_launch(void* const* d_in, const int* in_sizes, int n_in,
                              void* d_out, int out_size, void* d_ws, size_t ws_size,
                              hipStream_t stream)
{
    const float* x0    = (const float*)d_in[0];
    const float* t     = (const float*)d_in[1];
    const float* speed = (const float*)d_in[2];
    const float* vola  = (const float*)d_in[3];
    const float* adj   = (const float*)d_in[4];
    const float* noise = (const float*)d_in[5];
    const int*   items = (const int*)d_in[6];
    float* out = (float*)d_out;

    char* ws = (char*)d_ws;
    int*   cnt_part = (int*)ws;                       // 64 KB
    int*   deg      = (int*)(ws + 65536);             // 4 KB
    int*   pdeg     = (int*)(ws + 65536 + 4096);      // 4 KB
    int*   rank_of  = (int*)(ws + 65536 + 8192);      // 4 KB
    int*   node_of  = (int*)(ws + 65536 + 12288);     // 4 KB
    int*   ngrp_r   = (int*)(ws + 65536 + 16384);     // 4 KB
    float* invd_r   = (float*)(ws + 65536 + 20480);   // 4 KB
    u16*   nbrC     = (u16*)(ws + 65536 + 24576);     // 192 KB
    u16*   nbr8     = (u16*)(ws + 65536 + 24576 + 196608); // 192 KB

    k1_count<<<256, 64, 0, stream>>>(adj, cnt_part);
    k2_totals<<<4, 256, 0, stream>>>(cnt_part, deg, pdeg);
    k3_rank<<<4, 256, 0, stream>>>(pdeg, rank_of, node_of);
    k4_fill<<<256, 64, 0, stream>>>(adj, cnt_part, nbrC);
    k5_sched<<<16, 64, 0, stream>>>(nbrC, deg, pdeg, rank_of, nbr8, ngrp_r, invd_r);
    sim_kernel<<<64, 1024, 0, stream>>>(x0, t, speed, vola, noise, items,
                                        nbr8, node_of, ngrp_r, invd_r, out);
}

// Round 5
// 565.405 us; speedup vs baseline: 1.6431x; 1.0194x over previous
//
#include <hip/hip_runtime.h>

#define NN 1024
#define TT 256
#define MAXDEG 96

typedef unsigned short u16;

// LDS x-buffer layout (words): [0..1023] copy A (node m at word m, bank m&31)
//                              [1024..2047] copy B (node m at word 1024+permB(m), bank m>>5)
//                              [2048..2079] zero sentinels (one per bank)
// permB(m) = ((m&31)<<5) | (m>>5)  — bijective, bank(B) = m>>5 independent of bank(A) = m&31.

// ---- K1: per-chunk nonzero counts of each adj column (coalesced) ----
__global__ __launch_bounds__(64) void k1_count(const float* __restrict__ adj,
                                               int* __restrict__ cnt_part)
{
    int tid = blockIdx.x * 64 + threadIdx.x;
    int chunk = tid >> 10;
    int n = tid & 1023;
    int c = 0;
    for (int j = 0; j < 64; ++j)
        c += (adj[(chunk * 64 + j) * NN + n] != 0.0f) ? 1 : 0;
    cnt_part[chunk * NN + n] = c;
}

// ---- K2: totals -> deg, pdeg ----
__global__ __launch_bounds__(256) void k2_totals(const int* __restrict__ cnt_part,
                                                 int* __restrict__ deg,
                                                 int* __restrict__ pdeg)
{
    int n = blockIdx.x * 256 + threadIdx.x;
    int tot = 0;
    for (int c = 0; c < 16; ++c) tot += cnt_part[c * NN + n];
    deg[n] = tot;
    int cap = tot < MAXDEG ? tot : MAXDEG;
    int pd = (cap + 7) & ~7;
    if (pd < 16) pd = 16;
    pdeg[n] = pd;
}

// ---- K3: stable descending-degree rank ----
__global__ __launch_bounds__(256) void k3_rank(const int* __restrict__ pdeg,
                                               int* __restrict__ rank_of,
                                               int* __restrict__ node_of)
{
    int n = blockIdx.x * 256 + threadIdx.x;
    int my = pdeg[n];
    int r = 0;
    for (int m = 0; m < NN; ++m) {
        int pm = pdeg[m];
        r += (pm > my) || (pm == my && m < n);
    }
    rank_of[n] = r;
    node_of[r] = n;
}

// ---- K4: fill compact neighbor lists (coalesced column scan) ----
__global__ __launch_bounds__(64) void k4_fill(const float* __restrict__ adj,
                                              const int* __restrict__ cnt_part,
                                              u16* __restrict__ nbrC)
{
    int tid = blockIdx.x * 64 + threadIdx.x;
    int chunk = tid >> 10;
    int n = tid & 1023;
    int pos = 0;
    for (int c = 0; c < chunk; ++c) pos += cnt_part[c * NN + n];
    for (int j = 0; j < 64; ++j) {
        int m = chunk * 64 + j;
        if (adj[m * NN + n] != 0.0f) {
            if (pos < MAXDEG) nbrC[n * MAXDEG + pos] = (u16)m;
            ++pos;
        }
    }
}

// ---- K5: two-choice greedy bank schedule ----
// slot k of lane l targets bank (l+k)&31. Neighbor m may be read from copy A
// (bank m&31) or copy B (bank m>>5) — place first-fit on either residue.
__global__ __launch_bounds__(64) void k5_sched(const u16* __restrict__ nbrC,
                                               const int* __restrict__ deg,
                                               const int* __restrict__ pdeg,
                                               const int* __restrict__ rank_of,
                                               u16* __restrict__ nbr8,
                                               int* __restrict__ ngrp_r,
                                               float* __restrict__ invd_r)
{
    __shared__ u16 neigh[64][MAXDEG];
    __shared__ u16 slots[64][MAXDEG];   // word offset 0..2079, 0xFFFF = free
    const int tl = threadIdx.x;
    const int n  = blockIdx.x * 64 + tl;
    const int r  = rank_of[n];
    const int l  = r & 63;
    const int dg = deg[n];
    const int cap = dg < MAXDEG ? dg : MAXDEG;
    const int pd = pdeg[n];

    for (int j = 0; j < cap; ++j) neigh[tl][j] = nbrC[n * MAXDEG + j];
    for (int k = 0; k < MAXDEG; ++k) slots[tl][k] = 0xFFFF;

    int no = 0;
    for (int j = 0; j < cap; ++j) {
        u16 m = neigh[tl][j];
        int pB = (((int)m & 31) << 5) | ((int)m >> 5);
        int rA = (((int)m & 31) - l) & 31;
        int rB = ((((int)m >> 5) & 31) - l) & 31;
        int placed = 0;
        for (int k = rA; k < pd; k += 32)
            if (slots[tl][k] == 0xFFFF) { slots[tl][k] = m; placed = 1; break; }
        if (!placed)
            for (int k = rB; k < pd; k += 32)
                if (slots[tl][k] == 0xFFFF) { slots[tl][k] = (u16)(1024 + pB); placed = 1; break; }
        if (!placed) neigh[tl][no++] = m;
    }
    int fk = 0;
    for (int j = 0; j < no; ++j) {
        while (slots[tl][fk] != 0xFFFF) ++fk;
        slots[tl][fk] = neigh[tl][j];
    }
    for (int k = 0; k < MAXDEG; ++k) {   // write ALL 12 groups (sentinel-filled tail)
        u16 v = slots[tl][k];
        int wordoff = (v == 0xFFFF) ? (2048 + ((l + k) & 31)) : (int)v;
        nbr8[((k >> 3) << 13) + (r << 3) + (k & 7)] = (u16)(wordoff * 4);
    }
    ngrp_r[r] = pd >> 3;
    invd_r[r] = 0.35f / ((float)dg + 1e-7f);   // OMEGA*GAMMA/(in_deg+1e-7)
}

// ---------------- main simulation ----------------
__global__ __launch_bounds__(1024) void sim_kernel(
    const float* __restrict__ x0, const float* __restrict__ t,
    const float* __restrict__ speed, const float* __restrict__ vola,
    const float* __restrict__ noise, const int* __restrict__ items,
    const u16* __restrict__ nbr8, const int* __restrict__ node_of,
    const int* __restrict__ ngrp_r, const float* __restrict__ invd_r,
    float* __restrict__ out)
{
    __shared__ float xb[2][2080];       // A copy + B copy + 32 zero sentinels
    __shared__ float nzb[2][NN];        // staged noise, indexed by node id
    __shared__ float4 cst[TT - 1];      // per-step {e, scale, item_as_float, -}

    const int s   = blockIdx.x;
    const int tid = threadIdx.x;

    const float sp = speed[s];
    const float vo = vola[s];

    if (tid < TT - 1) {
        float t0 = t[s * TT + tid], t1 = t[s * TT + tid + 1];
        float dt = t1 - t0;
        float e  = expf(-sp * dt);
        float sc = vo * sqrtf((1.0f - e * e) / (2.0f * sp + 1e-6f));
        int   it = items[s * TT + tid + 1];
        cst[tid] = make_float4(e, sc, __int_as_float(it), 0.0f);
    }

    const float x0n = x0[tid];
    const int pBt = ((tid & 31) << 5) | (tid >> 5);
    xb[0][tid] = x0n;
    xb[0][1024 + pBt] = x0n;
    if (tid < 32) { xb[0][2048 + tid] = 0.0f; xb[1][2048 + tid] = 0.0f; }

    const float* __restrict__ nzp = noise + (size_t)s * (TT - 1) * NN + tid;
    nzb[0][tid] = nzp[0];

    float* __restrict__ outp = out + (size_t)s * TT * NN + tid;
    outp[0] = x0n;

    const int   m    = node_of[tid];      // node this thread simulates
    const int   wB   = 1024 + (((m & 31) << 5) | (m >> 5));   // copy-B write word
    const int   ng   = ngrp_r[tid];
    const float invd = invd_r[tid];
    const int   item0 = items[s * TT];
    float a_f = (m == item0) ? 1.0f : 0.0f;
    float s_f = 0.0f;

    // preload ALL neighbor index groups into registers (12 x uint4 = 8 u16 offsets each)
    const uint4* __restrict__ nb = (const uint4*)nbr8 + tid;   // group stride 1024
    uint4 q0  = nb[0];
    uint4 q1  = nb[1024];
    uint4 q2  = nb[2048];
    uint4 q3  = nb[3072];
    uint4 q4  = nb[4096];
    uint4 q5  = nb[5120];
    uint4 q6  = nb[6144];
    uint4 q7  = nb[7168];
    uint4 q8  = nb[8192];
    uint4 q9  = nb[9216];
    uint4 q10 = nb[10240];
    uint4 q11 = nb[11264];

    __syncthreads();

    float x_own = xb[0][m];

#define G8(V)                                                   \
    acc += *(const float*)(xc + ((V).x & 0xFFFFu));             \
    acc += *(const float*)(xc + ((V).x >> 16));                 \
    acc += *(const float*)(xc + ((V).y & 0xFFFFu));             \
    acc += *(const float*)(xc + ((V).y >> 16));                 \
    acc += *(const float*)(xc + ((V).z & 0xFFFFu));             \
    acc += *(const float*)(xc + ((V).z >> 16));                 \
    acc += *(const float*)(xc + ((V).w & 0xFFFFu));             \
    acc += *(const float*)(xc + ((V).w >> 16));

    for (int i = 0; i < TT - 1; ++i) {
        const float* __restrict__ src = xb[i & 1];
        float* __restrict__ dst       = xb[(i + 1) & 1];
        const float4 c = cst[i];

        float xi_lin = src[tid];          // prev value of node `tid` (linear, conflict-free)

        float acc = 0.0f;
        const char* xc = (const char*)src;
        G8(q0); G8(q1);
        if (ng > 2) { G8(q2);
        if (ng > 3) { G8(q3);
        if (ng > 4) { G8(q4);
        if (ng > 5) { G8(q5);
        if (ng > 6) { G8(q6);
        if (ng > 7) { G8(q7);
        if (ng > 8) { G8(q8);
        if (ng > 9) { G8(q9);
        if (ng > 10){ G8(q10);
        if (ng > 11){ G8(q11); } } } } } } } } } }

        float nz = nzb[i & 1][m] * c.y;
        float r  = s_f / (a_f + 1e-6f);
        float level = fmaf(acc, invd, 0.5f * r * r);
        float xn = fmaf(x_own, c.x, fmaf(1.0f - c.x, level, nz));

        dst[m]  = xn;                     // scatter write, copy A
        dst[wB] = xn;                     // scatter write, copy B
        if (i) outp[(size_t)i * NN] = xi_lin;          // coalesced, 1-step delayed
        if (i < TT - 2) nzb[(i + 1) & 1][tid] = nzp[(size_t)(i + 1) * NN];

        if (m == __float_as_int(c.z)) {
            a_f += 1.0f;
            s_f += (xn >= 0.0f) ? 1.0f : 0.0f;
        }
        x_own = xn;
        __syncthreads();
    }
#undef G8

    outp[(size_t)(TT - 1) * NN] = xb[1][tid];   // step 255 lands in buffer 1 (copy A linear)
}

extern "C" void kernel_launch(void* const* d_in, const int* in_sizes, int n_in,
                              void* d_out, int out_size, void* d_ws, size_t ws_size,
                              hipStream_t stream)
{
    const float* x0    = (const float*)d_in[0];
    const float* t     = (const float*)d_in[1];
    const float* speed = (const float*)d_in[2];
    const float* vola  = (const float*)d_in[3];
    const float* adj   = (const float*)d_in[4];
    const float* noise = (const float*)d_in[5];
    const int*   items = (const int*)d_in[6];
    float* out = (float*)d_out;

    char* ws = (char*)d_ws;
    int*   cnt_part = (int*)ws;                       // 64 KB
    int*   deg      = (int*)(ws + 65536);             // 4 KB
    int*   pdeg     = (int*)(ws + 65536 + 4096);      // 4 KB
    int*   rank_of  = (int*)(ws + 65536 + 8192);      // 4 KB
    int*   node_of  = (int*)(ws + 65536 + 12288);     // 4 KB
    int*   ngrp_r   = (int*)(ws + 65536 + 16384);     // 4 KB
    float* invd_r   = (float*)(ws + 65536 + 20480);   // 4 KB
    u16*   nbrC     = (u16*)(ws + 65536 + 24576);     // 192 KB
    u16*   nbr8     = (u16*)(ws + 65536 + 24576 + 196608); // 192 KB

    k1_count<<<256, 64, 0, stream>>>(adj, cnt_part);
    k2_totals<<<4, 256, 0, stream>>>(cnt_part, deg, pdeg);
    k3_rank<<<4, 256, 0, stream>>>(pdeg, rank_of, node_of);
    k4_fill<<<256, 64, 0, stream>>>(adj, cnt_part, nbrC);
    k5_sched<<<16, 64, 0, stream>>>(nbrC, deg, pdeg, rank_of, nbr8, ngrp_r, invd_r);
    sim_kernel<<<64, 1024, 0, stream>>>(x0, t, speed, vola, noise, items,
                                        nbr8, node_of, ngrp_r, invd_r, out);
}

// Round 6
// 533.228 us; speedup vs baseline: 1.7422x; 1.0603x over previous
//
#include <hip/hip_runtime.h>

#define NN 1024
#define TT 256
#define MAXDEG 96

typedef unsigned short u16;

// LDS x-buffer layout (words): [0..1023] copy A (node m at word m, bank m&31)
//                              [1024..2047] copy B (node m at word 1024+permB(m), bank m>>5)
//                              [2048..2079] zero sentinels (one per bank)
// permB(m) = ((m&31)<<5) | (m>>5)  — bijective, bank(B) = m>>5 independent of bank(A) = m&31.

// ---- K1: per-chunk nonzero counts of each adj column (coalesced) ----
__global__ __launch_bounds__(64) void k1_count(const float* __restrict__ adj,
                                               int* __restrict__ cnt_part)
{
    int tid = blockIdx.x * 64 + threadIdx.x;
    int chunk = tid >> 10;
    int n = tid & 1023;
    int c = 0;
    for (int j = 0; j < 64; ++j)
        c += (adj[(chunk * 64 + j) * NN + n] != 0.0f) ? 1 : 0;
    cnt_part[chunk * NN + n] = c;
}

// ---- K2: totals -> deg, pdeg ----
__global__ __launch_bounds__(256) void k2_totals(const int* __restrict__ cnt_part,
                                                 int* __restrict__ deg,
                                                 int* __restrict__ pdeg)
{
    int n = blockIdx.x * 256 + threadIdx.x;
    int tot = 0;
    for (int c = 0; c < 16; ++c) tot += cnt_part[c * NN + n];
    deg[n] = tot;
    int cap = tot < MAXDEG ? tot : MAXDEG;
    int pd = (cap + 7) & ~7;
    if (pd < 16) pd = 16;
    pdeg[n] = pd;
}

// ---- K3: stable descending-degree rank ----
__global__ __launch_bounds__(256) void k3_rank(const int* __restrict__ pdeg,
                                               int* __restrict__ rank_of,
                                               int* __restrict__ node_of)
{
    int n = blockIdx.x * 256 + threadIdx.x;
    int my = pdeg[n];
    int r = 0;
    for (int m = 0; m < NN; ++m) {
        int pm = pdeg[m];
        r += (pm > my) || (pm == my && m < n);
    }
    rank_of[n] = r;
    node_of[r] = n;
}

// ---- K4: fill compact neighbor lists (coalesced column scan) ----
__global__ __launch_bounds__(64) void k4_fill(const float* __restrict__ adj,
                                              const int* __restrict__ cnt_part,
                                              u16* __restrict__ nbrC)
{
    int tid = blockIdx.x * 64 + threadIdx.x;
    int chunk = tid >> 10;
    int n = tid & 1023;
    int pos = 0;
    for (int c = 0; c < chunk; ++c) pos += cnt_part[c * NN + n];
    for (int j = 0; j < 64; ++j) {
        int m = chunk * 64 + j;
        if (adj[m * NN + n] != 0.0f) {
            if (pos < MAXDEG) nbrC[n * MAXDEG + pos] = (u16)m;
            ++pos;
        }
    }
}

// ---- K5: two-choice greedy bank schedule ----
__global__ __launch_bounds__(64) void k5_sched(const u16* __restrict__ nbrC,
                                               const int* __restrict__ deg,
                                               const int* __restrict__ pdeg,
                                               const int* __restrict__ rank_of,
                                               u16* __restrict__ nbr8,
                                               int* __restrict__ ngrp_r,
                                               float* __restrict__ invd_r)
{
    __shared__ u16 neigh[64][MAXDEG];
    __shared__ u16 slots[64][MAXDEG];   // word offset 0..2079, 0xFFFF = free
    const int tl = threadIdx.x;
    const int n  = blockIdx.x * 64 + tl;
    const int r  = rank_of[n];
    const int l  = r & 63;
    const int dg = deg[n];
    const int cap = dg < MAXDEG ? dg : MAXDEG;
    const int pd = pdeg[n];

    for (int j = 0; j < cap; ++j) neigh[tl][j] = nbrC[n * MAXDEG + j];
    for (int k = 0; k < MAXDEG; ++k) slots[tl][k] = 0xFFFF;

    int no = 0;
    for (int j = 0; j < cap; ++j) {
        u16 m = neigh[tl][j];
        int pB = (((int)m & 31) << 5) | ((int)m >> 5);
        int rA = (((int)m & 31) - l) & 31;
        int rB = ((((int)m >> 5) & 31) - l) & 31;
        int placed = 0;
        for (int k = rA; k < pd; k += 32)
            if (slots[tl][k] == 0xFFFF) { slots[tl][k] = m; placed = 1; break; }
        if (!placed)
            for (int k = rB; k < pd; k += 32)
                if (slots[tl][k] == 0xFFFF) { slots[tl][k] = (u16)(1024 + pB); placed = 1; break; }
        if (!placed) neigh[tl][no++] = m;
    }
    int fk = 0;
    for (int j = 0; j < no; ++j) {
        while (slots[tl][fk] != 0xFFFF) ++fk;
        slots[tl][fk] = neigh[tl][j];
    }
    for (int k = 0; k < MAXDEG; ++k) {   // write ALL 12 groups (sentinel-filled tail)
        u16 v = slots[tl][k];
        int wordoff = (v == 0xFFFF) ? (2048 + ((l + k) & 31)) : (int)v;
        nbr8[((k >> 3) << 13) + (r << 3) + (k & 7)] = (u16)(wordoff * 4);
    }
    ngrp_r[r] = pd >> 3;
    invd_r[r] = 0.35f / ((float)dg + 1e-7f);   // OMEGA*GAMMA/(in_deg+1e-7)
}

// LDS-only barrier: order LDS ops, do NOT drain vmcnt (global loads/stores keep flying).
#define LDS_BARRIER() asm volatile("s_waitcnt lgkmcnt(0)\n\ts_barrier" ::: "memory")

// ---------------- main simulation ----------------
__global__ __launch_bounds__(1024) void sim_kernel(
    const float* __restrict__ x0, const float* __restrict__ t,
    const float* __restrict__ speed, const float* __restrict__ vola,
    const float* __restrict__ noise, const int* __restrict__ items,
    const u16* __restrict__ nbr8, const int* __restrict__ node_of,
    const int* __restrict__ ngrp_r, const float* __restrict__ invd_r,
    float* __restrict__ out)
{
    __shared__ float xb[2][2080];       // A copy + B copy + 32 zero sentinels
    __shared__ float4 cst[TT - 1];      // per-step {e, scale, item_as_float, -}

    const int s   = blockIdx.x;
    const int tid = threadIdx.x;

    const float sp = speed[s];
    const float vo = vola[s];

    if (tid < TT - 1) {
        float t0 = t[s * TT + tid], t1 = t[s * TT + tid + 1];
        float dt = t1 - t0;
        float e  = expf(-sp * dt);
        float sc = vo * sqrtf((1.0f - e * e) / (2.0f * sp + 1e-6f));
        int   it = items[s * TT + tid + 1];
        cst[tid] = make_float4(e, sc, __int_as_float(it), 0.0f);
    }

    const float x0n = x0[tid];
    const int pBt = ((tid & 31) << 5) | (tid >> 5);
    xb[0][tid] = x0n;
    xb[0][1024 + pBt] = x0n;
    if (tid < 32) { xb[0][2048 + tid] = 0.0f; xb[1][2048 + tid] = 0.0f; }

    float* __restrict__ outp = out + (size_t)s * TT * NN + tid;
    outp[0] = x0n;

    const int   m    = node_of[tid];      // node this thread simulates
    const int   wB   = 1024 + (((m & 31) << 5) | (m >> 5));   // copy-B write word
    const int   ng   = ngrp_r[tid];
    const float invd = invd_r[tid];
    const int   item0 = items[s * TT];
    float a_f = (m == item0) ? 1.0f : 0.0f;
    float s_f = 0.0f;

    // per-node noise pointer (register pipeline, 2 steps ahead)
    const float* __restrict__ nzm = noise + (size_t)s * (TT - 1) * NN + m;
    float nzA = nzm[0];                       // noise_0
    float nzB = nzm[NN];                      // noise_1

    // preload ALL neighbor index groups into registers (12 x uint4 = 8 u16 offsets each)
    const uint4* __restrict__ nb = (const uint4*)nbr8 + tid;   // group stride 1024
    uint4 q0  = nb[0];
    uint4 q1  = nb[1024];
    uint4 q2  = nb[2048];
    uint4 q3  = nb[3072];
    uint4 q4  = nb[4096];
    uint4 q5  = nb[5120];
    uint4 q6  = nb[6144];
    uint4 q7  = nb[7168];
    uint4 q8  = nb[8192];
    uint4 q9  = nb[9216];
    uint4 q10 = nb[10240];
    uint4 q11 = nb[11264];

    __syncthreads();                          // one full barrier after init

    float x_own = xb[0][m];

#define G8(V)                                                   \
    acc += *(const float*)(xc + ((V).x & 0xFFFFu));             \
    acc += *(const float*)(xc + ((V).x >> 16));                 \
    acc += *(const float*)(xc + ((V).y & 0xFFFFu));             \
    acc += *(const float*)(xc + ((V).y >> 16));                 \
    acc += *(const float*)(xc + ((V).z & 0xFFFFu));             \
    acc += *(const float*)(xc + ((V).z >> 16));                 \
    acc += *(const float*)(xc + ((V).w & 0xFFFFu));             \
    acc += *(const float*)(xc + ((V).w >> 16));

    for (int i = 0; i < TT - 1; ++i) {
        const float* __restrict__ src = xb[i & 1];
        float* __restrict__ dst       = xb[(i + 1) & 1];
        const float4 c = cst[i];

        // prefetch noise for step i+2 (clamped; latency hidden across 2 barriers)
        int ipre = (i + 2 < TT - 1) ? (i + 2) : (TT - 2);
        float nz_new = nzm[(size_t)ipre * NN];

        float xi_lin = src[tid];          // prev value of node `tid` (linear, conflict-free)

        float acc = 0.0f;
        const char* xc = (const char*)src;
        G8(q0); G8(q1);
        if (ng > 2) { G8(q2);
        if (ng > 3) { G8(q3);
        if (ng > 4) { G8(q4);
        if (ng > 5) { G8(q5);
        if (ng > 6) { G8(q6);
        if (ng > 7) { G8(q7);
        if (ng > 8) { G8(q8);
        if (ng > 9) { G8(q9);
        if (ng > 10){ G8(q10);
        if (ng > 11){ G8(q11); } } } } } } } } } }

        float nz = nzA * c.y;
        float r  = s_f / (a_f + 1e-6f);
        float level = fmaf(acc, invd, 0.5f * r * r);
        float xn = fmaf(x_own, c.x, fmaf(1.0f - c.x, level, nz));

        dst[m]  = xn;                     // scatter write, copy A
        dst[wB] = xn;                     // scatter write, copy B
        if (i) outp[(size_t)i * NN] = xi_lin;          // coalesced, 1-step delayed

        if (m == __float_as_int(c.z)) {
            a_f += 1.0f;
            s_f += (xn >= 0.0f) ? 1.0f : 0.0f;
        }
        x_own = xn;
        nzA = nzB; nzB = nz_new;
        LDS_BARRIER();                    // LDS-only: no vmcnt drain
    }
#undef G8

    outp[(size_t)(TT - 1) * NN] = xb[1][tid];   // step 255 lands in buffer 1 (copy A linear)
}

extern "C" void kernel_launch(void* const* d_in, const int* in_sizes, int n_in,
                              void* d_out, int out_size, void* d_ws, size_t ws_size,
                              hipStream_t stream)
{
    const float* x0    = (const float*)d_in[0];
    const float* t     = (const float*)d_in[1];
    const float* speed = (const float*)d_in[2];
    const float* vola  = (const float*)d_in[3];
    const float* adj   = (const float*)d_in[4];
    const float* noise = (const float*)d_in[5];
    const int*   items = (const int*)d_in[6];
    float* out = (float*)d_out;

    char* ws = (char*)d_ws;
    int*   cnt_part = (int*)ws;                       // 64 KB
    int*   deg      = (int*)(ws + 65536);             // 4 KB
    int*   pdeg     = (int*)(ws + 65536 + 4096);      // 4 KB
    int*   rank_of  = (int*)(ws + 65536 + 8192);      // 4 KB
    int*   node_of  = (int*)(ws + 65536 + 12288);     // 4 KB
    int*   ngrp_r   = (int*)(ws + 65536 + 16384);     // 4 KB
    float* invd_r   = (float*)(ws + 65536 + 20480);   // 4 KB
    u16*   nbrC     = (u16*)(ws + 65536 + 24576);     // 192 KB
    u16*   nbr8     = (u16*)(ws + 65536 + 24576 + 196608); // 192 KB

    k1_count<<<256, 64, 0, stream>>>(adj, cnt_part);
    k2_totals<<<4, 256, 0, stream>>>(cnt_part, deg, pdeg);
    k3_rank<<<4, 256, 0, stream>>>(pdeg, rank_of, node_of);
    k4_fill<<<256, 64, 0, stream>>>(adj, cnt_part, nbrC);
    k5_sched<<<16, 64, 0, stream>>>(nbrC, deg, pdeg, rank_of, nbr8, ngrp_r, invd_r);
    sim_kernel<<<64, 1024, 0, stream>>>(x0, t, speed, vola, noise, items,
                                        nbr8, node_of, ngrp_r, invd_r, out);
}